// Round 18
// baseline (734.532 us; speedup 1.0000x reference)
//
#include <hip/hip_runtime.h>

#define DEV __device__ __forceinline__

typedef __bf16 bf16x8 __attribute__((ext_vector_type(8)));
typedef float f32x4 __attribute__((ext_vector_type(4)));
typedef unsigned short u16;
typedef u16 u16x4 __attribute__((ext_vector_type(4)));

constexpr int T_ANS = 32768;        // N*La answer tokens
constexpr int LQ    = 64;
constexpr int M_ALL = T_ANS + LQ;   // 32832 rows fed to projection
constexpr int M_PAD = 33024;        // 258*128 (tile-padded)
constexpr int DIM   = 1024;

DEV u16 f2bf(float x) {
  unsigned u = __float_as_uint(x);
  return (u16)((u + 0x7FFFu + ((u >> 16) & 1u)) >> 16);
}
DEV float bf2f(u16 s) { return __uint_as_float(((unsigned)s) << 16); }

DEV void gl2lds16(const void* g, void* l) {
  __builtin_amdgcn_global_load_lds(
      (const __attribute__((address_space(1))) unsigned int*)g,
      (__attribute__((address_space(3))) unsigned int*)l, 16, 0, 0);
}

#define MF(A, B, C) __builtin_amdgcn_mfma_f32_16x16x32_bf16(A, B, C, 0, 0, 0)
#define LFC(P, OFF) (*(const bf16x8*)((P) + (OFF)))

// ---------------- v3 core: 256x256, BK=32, 4 LDS buffers, 1 barrier/tile ----------
// Swizzle v3 (octet-bijective, HW-verified R15: conflicts -> 0): phys k-block =
// logical ^ ((row>>1)&3); per-octet 16B-slot (addr[6:4]) bijective over row&7.
// Stage: linear LDS dest + inverse-permuted global source (rule 21 matched pair).
// Counted vmcnt(4); no setprio / sched_barrier / lgkm asm.

#define STG(G, LT, R0) gl2lds16((G) + (R0) * 2048 + gOff, (LT) + (R0) * 64 + ldOff)

#define S_TILE(AT, BT, BUF)                                                           \
  { const char* ga_ = (AT); const char* gb_ = (BT); char* lb_ = (BUF);                \
    STG(ga_, lb_, 0); STG(ga_, lb_, 128);                                             \
    STG(gb_, lb_ + 16384, 0); STG(gb_, lb_ + 16384, 128); }

#define VMC4 asm volatile("s_waitcnt vmcnt(4)" ::: "memory");
#define VMC0 asm volatile("s_waitcnt vmcnt(0)" ::: "memory");

#define TILEV3(BUF, STAGES, WAIT)                                                     \
  {                                                                                   \
    STAGES                                                                            \
    const char* Ar = (BUF) + rdA;                                                     \
    const char* Br = (BUF) + 16384 + rdB;                                             \
    bf16x8 a0 = LFC(Ar, 0),    a1 = LFC(Ar, 1024), a2 = LFC(Ar, 2048), a3 = LFC(Ar, 3072); \
    bf16x8 a4 = LFC(Ar, 4096), a5 = LFC(Ar, 5120), a6 = LFC(Ar, 6144), a7 = LFC(Ar, 7168); \
    bf16x8 c0 = LFC(Br, 0), c1 = LFC(Br, 1024), c2 = LFC(Br, 2048), c3 = LFC(Br, 3072);    \
    acc[0][0] = MF(a0, c0, acc[0][0]); acc[0][1] = MF(a0, c1, acc[0][1]);             \
    acc[0][2] = MF(a0, c2, acc[0][2]); acc[0][3] = MF(a0, c3, acc[0][3]);             \
    acc[1][0] = MF(a1, c0, acc[1][0]); acc[1][1] = MF(a1, c1, acc[1][1]);             \
    acc[1][2] = MF(a1, c2, acc[1][2]); acc[1][3] = MF(a1, c3, acc[1][3]);             \
    acc[2][0] = MF(a2, c0, acc[2][0]); acc[2][1] = MF(a2, c1, acc[2][1]);             \
    acc[2][2] = MF(a2, c2, acc[2][2]); acc[2][3] = MF(a2, c3, acc[2][3]);             \
    acc[3][0] = MF(a3, c0, acc[3][0]); acc[3][1] = MF(a3, c1, acc[3][1]);             \
    acc[3][2] = MF(a3, c2, acc[3][2]); acc[3][3] = MF(a3, c3, acc[3][3]);             \
    acc[4][0] = MF(a4, c0, acc[4][0]); acc[4][1] = MF(a4, c1, acc[4][1]);             \
    acc[4][2] = MF(a4, c2, acc[4][2]); acc[4][3] = MF(a4, c3, acc[4][3]);             \
    acc[5][0] = MF(a5, c0, acc[5][0]); acc[5][1] = MF(a5, c1, acc[5][1]);             \
    acc[5][2] = MF(a5, c2, acc[5][2]); acc[5][3] = MF(a5, c3, acc[5][3]);             \
    acc[6][0] = MF(a6, c0, acc[6][0]); acc[6][1] = MF(a6, c1, acc[6][1]);             \
    acc[6][2] = MF(a6, c2, acc[6][2]); acc[6][3] = MF(a6, c3, acc[6][3]);             \
    acc[7][0] = MF(a7, c0, acc[7][0]); acc[7][1] = MF(a7, c1, acc[7][1]);             \
    acc[7][2] = MF(a7, c2, acc[7][2]); acc[7][3] = MF(a7, c3, acc[7][3]);             \
    WAIT                                                                              \
    asm volatile("s_barrier" ::: "memory");                                           \
  }

#define CORE_BASES                                                                    \
  const int ldOff = tid * 16;                                                         \
  const int gOff = (tid >> 2) * 2048 + (((tid & 3) ^ ((tid >> 3) & 3)) << 4);         \
  const int blk_ = (((lane >> 4) ^ ((lane >> 1) & 3)) << 4);                          \
  const int rdA = (wm + (lane & 15)) * 64 + blk_;                                     \
  const int rdB = (wn + (lane & 15)) * 64 + blk_;                                     \
  char* b0_ = lds; char* b1_ = lds + 32768; char* b2_ = lds + 65536; char* b3_ = lds + 98304;

#define GROUP4(T0)                                                                    \
    TILEV3(b0_, S_TILE(Ab((T0) + 2), Bb((T0) + 2), b2_), VMC4)                        \
    TILEV3(b1_, S_TILE(Ab((T0) + 3), Bb((T0) + 3), b3_), VMC4)                        \
    TILEV3(b2_, S_TILE(Ab((T0) + 4), Bb((T0) + 4), b0_), VMC4)                        \
    TILEV3(b3_, S_TILE(Ab((T0) + 5), Bb((T0) + 5), b1_), VMC4)

// ---------------- prep_all: all elementwise prep in ONE dispatch -------------------
// ranges: [0,8192) pack_w12 | [8192,11264) cast lin | [11264,15360) conv_w1 |
// [15360,19456) conv_w2 | [19456,23552) conv_w3 | [23552,24320) zero cat |
// [24320,57344) gather_cast

__global__ __launch_bounds__(256)
void prep_all(const float* __restrict__ w1, const float* __restrict__ w2,
              u16* __restrict__ W12,
              const float* __restrict__ lin_w, u16* __restrict__ linb,
              const float* __restrict__ cw1, const float* __restrict__ cw2,
              const float* __restrict__ cw3, u16* __restrict__ cwb,
              float* __restrict__ cat,
              const int* __restrict__ dq, const int* __restrict__ das,
              const float* __restrict__ emb, u16* __restrict__ X) {
  const int b = blockIdx.x, t = threadIdx.x;
  if (b < 8192) {                      // pack_w12: 16-row interleave of w1/w2
    int i = b * 256 + t;               // over 2048*1024
    int n2 = i >> 10, k = i & 1023;
    int j = n2 >> 4, m = n2 & 15;
    const float* src = (j & 1) ? w2 : w1;
    W12[i] = f2bf(src[(size_t)((j >> 1) * 16 + m) * 1024 + k]);
  } else if (b < 11264) {              // cast lin_w (float4 -> u16x4)
    int i = (b - 8192) * 256 + t;      // over 786432 float4s
    float4 v = ((const float4*)lin_w)[i];
    u16x4 o = { f2bf(v.x), f2bf(v.y), f2bf(v.z), f2bf(v.w) };
    ((u16x4*)linb)[i] = o;
  } else if (b < 23552) {              // conv weights: cw[o][i][k] -> W slabs
    int rb = b - 11264;
    int W = 1 + (rb >> 12);            // 4096 blocks per W in {1,2,3}
    int i = (rb & 4095) * 256 + t;     // over 1024*1024
    const float* src = (W == 1) ? cw1 : (W == 2) ? cw2 : cw3;
    u16* dst = cwb + ((W == 1) ? 0 : (W == 2) ? (size_t)1 * 1048576 : (size_t)3 * 1048576);
#pragma unroll 3
    for (int k = 0; k < 3; ++k)
      if (k < W)
        dst[(size_t)k * 1048576 + i] = f2bf(src[(size_t)i * W + k]);
  } else if (b < 24320) {              // zero cat [64][3072] f32
    cat[(b - 23552) * 256 + t] = 0.f;
  } else {                             // gather_cast
    const int row = b - 24320;         // [0, M_PAD)
    size_t dsto = (size_t)row * DIM + t * 4;
    if (row >= M_ALL) {
      u16x4 z = {0, 0, 0, 0};
      *(u16x4*)(X + dsto) = z;
      return;
    }
    const int tok = (row < T_ANS) ? das[row] : dq[row - T_ANS];
    float4 v = ((const float4*)(emb + (size_t)tok * DIM))[t];
    u16x4 o = { f2bf(v.x), f2bf(v.y), f2bf(v.z), f2bf(v.w) };
    *(u16x4*)(X + dsto) = o;
  }
}

__global__ void transpose_pq(const u16* __restrict__ pa, u16* __restrict__ pqT) {
  int i = blockIdx.x * 256 + threadIdx.x;  // 1024*64
  int e = i >> 6, q = i & 63;
  pqT[i] = pa[(size_t)(T_ANS + q) * DIM + e];
}

__global__ void zero_pad_sim(u16* __restrict__ sim) {
  int i = blockIdx.x * 256 + threadIdx.x;
  if (i < 2 * DIM) sim[(size_t)T_ANS * DIM + i] = 0;
}

__global__ void cast_cat(const float* __restrict__ cat, u16* __restrict__ catb) {
  int i = blockIdx.x * 256 + threadIdx.x;  // 128*3072
  if (i < 128 * 3072) {
    int row = i / 3072;
    catb[i] = (row < 64) ? f2bf(cat[i]) : (u16)0;
  }
}

// ---------------- projection, m97 structure + octet-bijective swizzle (R15) --------

__global__ __launch_bounds__(256)
void proj_g(const u16* __restrict__ X, const u16* __restrict__ W12,
            const float* __restrict__ b1, const float* __restrict__ b2,
            u16* __restrict__ pa) {
  __shared__ alignas(16) u16 sA[128 * 32];
  __shared__ alignas(16) u16 sB[128 * 32];
  const int tid = threadIdx.x, lane = tid & 63;
  const int wid = tid >> 6;
  const int wm = (wid >> 1) * 64, wn = (wid & 1) * 64;
  // bijective XCD swizzle, tn fastest: 4128 = 8*516; 16 same-A blocks contiguous/XCD
  const int wg = ((int)blockIdx.x % 8) * 516 + (int)blockIdx.x / 8;
  const int tm = (wg >> 4) * 128, tn = (wg & 15) * 128;
  f32x4 acc[4][4] = {};
  for (int k0 = 0; k0 < 1024; k0 += 32) {
#pragma unroll
    for (int j = 0; j < 2; ++j) {
      const int f = tid * 16 + j * 4096;
      const int r = f >> 6;
      const int cb = (((f >> 4) & 3) ^ ((f >> 7) & 3)) << 4;  // inverse-swz source
      gl2lds16((const char*)X   + (size_t)(tm + r) * 2048 + k0 * 2 + cb, (char*)sA + f);
      gl2lds16((const char*)W12 + (size_t)(tn + r) * 2048 + k0 * 2 + cb, (char*)sB + f);
    }
    __syncthreads();
    const int lr = lane & 15;
    const int lk = ((lane >> 4) ^ ((lane >> 1) & 3)) * 8;      // swizzled 16B block
    bf16x8 af[4], bf[4];
#pragma unroll
    for (int i = 0; i < 4; ++i) {
      af[i] = *(const bf16x8*)(sA + (wm + i * 16 + lr) * 32 + lk);
      bf[i] = *(const bf16x8*)(sB + (wn + i * 16 + lr) * 32 + lk);
    }
#pragma unroll
    for (int mi = 0; mi < 4; ++mi)
#pragma unroll
      for (int ni = 0; ni < 4; ++ni)
        acc[mi][ni] = MF(af[mi], bf[ni], acc[mi][ni]);
    __syncthreads();
  }
  // epilogue: W12 interleave -> (sig, tanh) pairs at (ni, ni+1), ni even
  const int lr = lane & 15, lg = (lane >> 4) * 4;
#pragma unroll
  for (int np = 0; np < 2; ++np) {
    const int col = ((tn + wn) >> 1) + np * 16 + lr;   // output col 0..1023
    const float b1v = b1[col], b2v = b2[col];
#pragma unroll
    for (int mi = 0; mi < 4; ++mi)
#pragma unroll
      for (int r = 0; r < 4; ++r) {
        const int row = tm + wm + mi * 16 + lg + r;
        const float x1 = acc[mi][2 * np][r] + b1v;
        const float x2 = acc[mi][2 * np + 1][r] + b2v;
        const float sg = 1.f / (1.f + __expf(-x1));
        const float th = 2.f / (1.f + __expf(-2.f * x2)) - 1.f;
        pa[(size_t)row * DIM + col] = f2bf(sg * th);
      }
  }
}

// ---------------- conv_fused: 2 N-tiles glued, one continuous 384-tile pipeline ----
// Grid 256 = 1 block/CU. Per block: tm fixed, two tn values (tn0, tn0+512).
// Unified t in [0,384): seg = t>=192 selects tn; tl = t%192; slab = tl>>5;
// A-tap(g) = g-(g>0)-2*(g>2). Seam tiles 190-193 pipeline across the tn switch
// (R14-proven glue pattern: independent B slabs, same A). Epilogues at t =
// 32/96/192/224/288/384 (all GROUP4-aligned; register-only + atomics).

__global__ __launch_bounds__(512, 1)
void conv_fused(const u16* __restrict__ sim, const u16* __restrict__ cwb,
                const float* __restrict__ cb1, const float* __restrict__ cb2,
                const float* __restrict__ cb3, float* __restrict__ cat) {
  extern __shared__ char lds[];
  const int tid = threadIdx.x, lane = tid & 63;
  const int wid = tid >> 6;
  const int wm = (wid >> 2) * 128, wn = (wid & 3) * 64;
  const int lr = lane & 15;
  // bijective XCD swizzle: 256 = 8*32; same-A pair (both tn) adjacent per XCD
  const int wg = ((int)blockIdx.x % 8) * 32 + (int)blockIdx.x / 8;
  const int tm = (wg >> 1) * 256;
  const int tn0 = (wg & 1) * 256, tn1 = tn0 + 512;
  const char* Ag = (const char*)sim + (size_t)tm * 2048;
  auto Ab = [&](int t) {
    const int tl = (t >= 192) ? t - 192 : t;
    const int g = tl >> 5;
    const int tap = g - (g > 0) - 2 * (g > 2);   // {0,0,1,0,1,2}
    return Ag + tap * 2048 + ((tl & 31) << 6);
  };
  auto Bb = [&](int t) {
    const int tl = (t >= 192) ? t - 192 : t;
    const char* Bg = (const char*)cwb + (size_t)((t >= 192) ? tn1 : tn0) * 2048;
    return Bg + (size_t)(tl >> 5) * 2097152 + ((tl & 31) << 6);
  };

  f32x4 acc[8][4] = {};
  CORE_BASES

  const int lg = (lane >> 4) * 4;
  const int n = tm >> 9;  // 256 | 512 so one answer per tile
  auto epi = [&](int W, const float* cb, int outoff, int tnx) {
#pragma unroll
    for (int ni = 0; ni < 4; ++ni) {
      const int col = tnx + wn + ni * 16 + lr;
      const float cbv = cb[col];
      float vmax = 0.f;
#pragma unroll
      for (int mi = 0; mi < 8; ++mi)
#pragma unroll
        for (int r = 0; r < 4; ++r) {
          const int t = tm + wm + mi * 16 + lg + r;
          float v = fmaxf(acc[mi][ni][r] + cbv, 0.f);
          if ((t & 511) > 512 - W) v = 0.f;  // window straddles answer boundary
          vmax = fmaxf(vmax, v);
        }
      vmax = fmaxf(vmax, __shfl_xor(vmax, 16));
      vmax = fmaxf(vmax, __shfl_xor(vmax, 32));
      if (lane < 16)
        atomicMax((int*)&cat[(size_t)n * 3072 + outoff + col], __float_as_int(vmax));
    }
#pragma unroll
    for (int i = 0; i < 8; ++i)
#pragma unroll
      for (int j = 0; j < 4; ++j) acc[i][j] = (f32x4){0.f, 0.f, 0.f, 0.f};
  };

  S_TILE(Ab(0), Bb(0), b0_) S_TILE(Ab(1), Bb(1), b1_)
  VMC4
  asm volatile("s_barrier" ::: "memory");
  for (int g = 0; g < 8; ++g) { GROUP4(4 * g) }          // t 0..31   (seg0 conv1)
  epi(1, cb1, 0, tn0);
  for (int g = 8; g < 24; ++g) { GROUP4(4 * g) }         // t 32..95  (seg0 conv2)
  epi(2, cb2, 1024, tn0);
  for (int g = 24; g < 48; ++g) { GROUP4(4 * g) }        // t 96..191 (seg0 conv3; stages cross seam)
  epi(3, cb3, 2048, tn0);
  for (int g = 48; g < 56; ++g) { GROUP4(4 * g) }        // t 192..223 (seg1 conv1)
  epi(1, cb1, 0, tn1);
  for (int g = 56; g < 72; ++g) { GROUP4(4 * g) }        // t 224..287 (seg1 conv2)
  epi(2, cb2, 1024, tn1);
  for (int g = 72; g < 95; ++g) { GROUP4(4 * g) }        // t 288..379 (seg1 conv3)
  {
    TILEV3(b0_, S_TILE(Ab(382), Bb(382), b2_), VMC4)     // t 380..383 + drain
    TILEV3(b1_, S_TILE(Ab(383), Bb(383), b3_), VMC4)
    TILEV3(b2_, , VMC0)
    TILEV3(b3_, , )
  }
  epi(3, cb3, 2048, tn1);
}

// ---------------- attention S = pa @ pq^T  (split-K x4, deterministic partials) ----

__global__ __launch_bounds__(256, 2)
void attn_s(const u16* __restrict__ pa, float* __restrict__ Spart) {
  __shared__ alignas(16) u16 sA[128 * 32];
  __shared__ alignas(16) u16 sB[64 * 32];
  const int tid = threadIdx.x, lane = tid & 63;
  const int tm = blockIdx.x * 128;
  const int kbase = blockIdx.y * 256;     // K chunk of 256
  const int wid = tid >> 6;
  const int wm = (wid >> 1) * 64, wn = (wid & 1) * 32;
  const u16* pq = pa + (size_t)T_ANS * DIM;
  f32x4 acc[4][2] = {};
  for (int k0 = kbase; k0 < kbase + 256; k0 += 32) {
#pragma unroll
    for (int j = 0; j < 2; ++j) {
      const int f = tid * 16 + j * 4096;
      const int r = f >> 6, cb = f & 63;
      gl2lds16((const char*)pa + (size_t)(tm + r) * 2048 + k0 * 2 + cb, (char*)sA + f);
    }
    {
      const int f = tid * 16;  // 4 KB, single issue
      const int r = f >> 6, cb = f & 63;
      gl2lds16((const char*)pq + (size_t)r * 2048 + k0 * 2 + cb, (char*)sB + f);
    }
    __syncthreads();
    const int lr = lane & 15, lk = (lane >> 4) * 8;
    bf16x8 af[4], bfr[2];
#pragma unroll
    for (int i = 0; i < 4; ++i)
      af[i] = *(const bf16x8*)(sA + (wm + i * 16 + lr) * 32 + lk);
#pragma unroll
    for (int i = 0; i < 2; ++i)
      bfr[i] = *(const bf16x8*)(sB + (wn + i * 16 + lr) * 32 + lk);
#pragma unroll
    for (int mi = 0; mi < 4; ++mi)
#pragma unroll
      for (int ni = 0; ni < 2; ++ni)
        acc[mi][ni] = MF(af[mi], bfr[ni], acc[mi][ni]);
    __syncthreads();
  }
  const int lr = lane & 15, lg = (lane >> 4) * 4;
  float* Sp = Spart + (size_t)blockIdx.y * (T_ANS * 64);
#pragma unroll
  for (int mi = 0; mi < 4; ++mi)
#pragma unroll
    for (int ni = 0; ni < 2; ++ni)
#pragma unroll
      for (int r = 0; r < 4; ++r) {
        const int row = tm + wm + mi * 16 + lg + r;
        const int col = wn + ni * 16 + lr;
        Sp[(size_t)row * 64 + col] = acc[mi][ni][r];
      }
}

__global__ void softmax64(const float* __restrict__ Spart, u16* __restrict__ alpha) {
  const int row = blockIdx.x * 4 + (threadIdx.x >> 6);
  const int lane = threadIdx.x & 63;
  const size_t o = (size_t)row * 64 + lane;
  float v = Spart[o] + Spart[(size_t)1 * T_ANS * 64 + o]
          + Spart[(size_t)2 * T_ANS * 64 + o] + Spart[(size_t)3 * T_ANS * 64 + o];
  float m = v;
#pragma unroll
  for (int o2 = 32; o2 > 0; o2 >>= 1) m = fmaxf(m, __shfl_xor(m, o2));
  const float e = __expf(v - m);
  float s = e;
#pragma unroll
  for (int o2 = 32; o2 > 0; o2 >>= 1) s += __shfl_xor(s, o2);
  alpha[(size_t)row * 64 + lane] = f2bf(e / s);
}

// ---------------- Y = alpha @ pq ; sim = pa * Y ----------------

__global__ __launch_bounds__(256, 2)
void attn_y_sim(const u16* __restrict__ alpha, const u16* __restrict__ pqT,
                const u16* __restrict__ pa, u16* __restrict__ sim) {
  __shared__ alignas(16) u16 sA[128 * 32];
  __shared__ alignas(16) u16 sB[128 * 32];
  const int tid = threadIdx.x, lane = tid & 63;
  const int tm = blockIdx.x * 128, tn = blockIdx.y * 128;
  const int wid = tid >> 6;
  const int wm = (wid >> 1) * 64, wn = (wid & 1) * 64;
  f32x4 acc[4][4] = {};
  for (int k0 = 0; k0 < 64; k0 += 32) {
#pragma unroll
    for (int j = 0; j < 2; ++j) {
      const int f = tid * 16 + j * 4096;
      const int r = f >> 6, cb = f & 63;
      gl2lds16((const char*)alpha + (size_t)(tm + r) * 128 + k0 * 2 + cb, (char*)sA + f);
      gl2lds16((const char*)pqT   + (size_t)(tn + r) * 128 + k0 * 2 + cb, (char*)sB + f);
    }
    __syncthreads();
    const int lr = lane & 15, lk = (lane >> 4) * 8;
    bf16x8 af[4], bfr[4];
#pragma unroll
    for (int i = 0; i < 4; ++i) {
      af[i]  = *(const bf16x8*)(sA + (wm + i * 16 + lr) * 32 + lk);
      bfr[i] = *(const bf16x8*)(sB + (wn + i * 16 + lr) * 32 + lk);
    }
#pragma unroll
    for (int mi = 0; mi < 4; ++mi)
#pragma unroll
      for (int ni = 0; ni < 4; ++ni)
        acc[mi][ni] = MF(af[mi], bfr[ni], acc[mi][ni]);
    __syncthreads();
  }
  const int lr = lane & 15, lg = (lane >> 4) * 4;
#pragma unroll
  for (int ni = 0; ni < 4; ++ni) {
    const int col = tn + wn + ni * 16 + lr;
#pragma unroll
    for (int mi = 0; mi < 4; ++mi)
#pragma unroll
      for (int r = 0; r < 4; ++r) {
        const int row = tm + wm + mi * 16 + lg + r;
        const size_t o = (size_t)row * DIM + col;
        sim[o] = f2bf(bf2f(pa[o]) * acc[mi][ni][r]);
      }
  }
}

// ---------------- final: h = tanh(cat @ lin^T + b) ----------------

__global__ __launch_bounds__(256, 2)
void final_h(const u16* __restrict__ catb, const u16* __restrict__ linb,
             const float* __restrict__ lin_b, float* __restrict__ h) {
  __shared__ alignas(16) u16 sA[128 * 32];
  __shared__ alignas(16) u16 sB[128 * 32];
  const int tid = threadIdx.x, lane = tid & 63;
  const int tn = blockIdx.y * 128;
  const int wid = tid >> 6;
  const int wm = (wid >> 1) * 64, wn = (wid & 1) * 64;
  f32x4 acc[4][4] = {};
  for (int k0 = 0; k0 < 3072; k0 += 32) {
#pragma unroll
    for (int j = 0; j < 2; ++j) {
      const int f = tid * 16 + j * 4096;
      const int r = f >> 6, cb = f & 63;
      gl2lds16((const char*)catb + (size_t)r * 6144 + k0 * 2 + cb, (char*)sA + f);
      gl2lds16((const char*)linb + (size_t)(tn + r) * 6144 + k0 * 2 + cb, (char*)sB + f);
    }
    __syncthreads();
    const int lr = lane & 15, lk = (lane >> 4) * 8;
    bf16x8 af[4], bfr[4];
#pragma unroll
    for (int i = 0; i < 4; ++i) {
      af[i]  = *(const bf16x8*)(sA + (wm + i * 16 + lr) * 32 + lk);
      bfr[i] = *(const bf16x8*)(sB + (wn + i * 16 + lr) * 32 + lk);
    }
#pragma unroll
    for (int mi = 0; mi < 4; ++mi)
#pragma unroll
      for (int ni = 0; ni < 4; ++ni)
        acc[mi][ni] = MF(af[mi], bfr[ni], acc[mi][ni]);
    __syncthreads();
  }
  const int lr = lane & 15, lg = (lane >> 4) * 4;
#pragma unroll
  for (int ni = 0; ni < 4; ++ni) {
    const int col = tn + wn + ni * 16 + lr;
    const float bv = lin_b[col];
#pragma unroll
    for (int mi = 0; mi < 4; ++mi)
#pragma unroll
      for (int r = 0; r < 4; ++r) {
        const int row = wm + mi * 16 + lg + r;
        if (row < 64) {
          const float x = acc[mi][ni][r] + bv;
          h[(size_t)row * DIM + col] = 2.f / (1.f + __expf(-2.f * x)) - 1.f;
        }
      }
  }
}

__global__ void final_logits(const float* __restrict__ h, const float* __restrict__ soft_w,
                             const float* __restrict__ soft_b, float* __restrict__ out) {
  __shared__ float part[256];
  const int t = threadIdx.x;
  const int n = t >> 2, q = t & 3;
  float s = 0.f;
  for (int j = q * 256; j < q * 256 + 256; ++j) s += h[(size_t)n * DIM + j] * soft_w[j];
  part[t] = s;
  __syncthreads();
  if (t < 64) {
    float logit = part[t * 4] + part[t * 4 + 1] + part[t * 4 + 2] + part[t * 4 + 3] + soft_b[0];
    float m = logit;
#pragma unroll
    for (int o = 32; o > 0; o >>= 1) m = fmaxf(m, __shfl_xor(m, o));
    float e = __expf(logit - m);
    float ssum = e;
#pragma unroll
    for (int o = 32; o > 0; o >>= 1) ssum += __shfl_xor(ssum, o);
    out[t] = (logit - m) - logf(ssum);
  }
}

// ---------------- launcher ----------------

extern "C" void kernel_launch(void* const* d_in, const int* in_sizes, int n_in,
                              void* d_out, int out_size, void* d_ws, size_t ws_size,
                              hipStream_t stream) {
  const int*   data_q  = (const int*)d_in[0];
  const int*   data_as = (const int*)d_in[1];
  const float* emb     = (const float*)d_in[2];
  const float* w1      = (const float*)d_in[3];
  const float* b1      = (const float*)d_in[4];
  const float* w2      = (const float*)d_in[5];
  const float* b2      = (const float*)d_in[6];
  const float* cw1     = (const float*)d_in[7];
  const float* cb1     = (const float*)d_in[8];
  const float* cw2     = (const float*)d_in[9];
  const float* cb2     = (const float*)d_in[10];
  const float* cw3     = (const float*)d_in[11];
  const float* cb3     = (const float*)d_in[12];
  const float* lin_w   = (const float*)d_in[13];
  const float* lin_b   = (const float*)d_in[14];
  const float* soft_w  = (const float*)d_in[15];
  const float* soft_b  = (const float*)d_in[16];
  float* out = (float*)d_out;

  // allow 128 KiB dynamic LDS on the fused conv kernel (host attr set, capture-safe)
  hipFuncSetAttribute((const void*)conv_fused, hipFuncAttributeMaxDynamicSharedMemorySize, 131072);

  // workspace layout (~167 MB total)
  u16* X     = (u16*)d_ws;                         // [M_PAD][1024] bf16; reused: Spart, then sim
  u16* pa    = X    + (size_t)M_PAD * DIM;         // [M_PAD][1024] bf16 (rows T..T+63 = pq)
  u16* W12   = pa   + (size_t)M_PAD * DIM;         // [2048][1024] interleaved w1/w2
  u16* cwb   = W12  + (size_t)2 * 1024 * 1024;     // 6 x [1024][1024]
  u16* linb  = cwb  + (size_t)6 * 1024 * 1024;     // [1024][3072]
  u16* pqT   = linb + (size_t)3 * 1024 * 1024;     // [1024][64]
  u16* alpha = pqT  + 64 * 1024;                   // [T][64] bf16
  float* cat = (float*)(alpha + (size_t)T_ANS * 64);  // [64][3072] f32 pools
  u16* catb  = (u16*)(cat + 64 * 3072);            // [128][3072] bf16 (rows 64+ zero)
  float* h   = (float*)(catb + 128 * 3072);        // [64][1024] f32
  u16* simb  = X;                                  // alias: [T+2][1024] bf16
  float* Spart = (float*)X;                        // alias: [4][T][64] f32 (33.6 MB < 67 MB)

  prep_all<<<57344, 256, 0, stream>>>(w1, w2, W12, lin_w, linb, cw1, cw2, cw3, cwb,
                                      cat, data_q, data_as, emb, X);

  proj_g<<<4128, 256, 0, stream>>>(X, W12, b1, b2, pa);
  transpose_pq<<<256, 256, 0, stream>>>(pa, pqT);

  attn_s<<<dim3(T_ANS / 128, 4), 256, 0, stream>>>(pa, Spart);
  softmax64<<<T_ANS / 4, 256, 0, stream>>>(Spart, alpha);
  attn_y_sim<<<dim3(T_ANS / 128, 8), 256, 0, stream>>>(alpha, pqT, pa, simb);
  zero_pad_sim<<<8, 256, 0, stream>>>(simb);

  conv_fused<<<256, 512, 131072, stream>>>(simb, cwb, cb1, cb2, cb3, cat);

  cast_cat<<<1536, 256, 0, stream>>>(cat, catb);
  final_h<<<dim3(1, 8), 256, 0, stream>>>(catb, linb, lin_b, h);
  final_logits<<<1, 256, 0, stream>>>(h, soft_w, soft_b, out);
}

// Round 19
// 725.454 us; speedup vs baseline: 1.0125x; 1.0125x over previous
//
#include <hip/hip_runtime.h>

#define DEV __device__ __forceinline__

typedef __bf16 bf16x8 __attribute__((ext_vector_type(8)));
typedef float f32x4 __attribute__((ext_vector_type(4)));
typedef unsigned short u16;
typedef u16 u16x4 __attribute__((ext_vector_type(4)));

constexpr int T_ANS = 32768;        // N*La answer tokens
constexpr int LQ    = 64;
constexpr int M_ALL = T_ANS + LQ;   // 32832 rows fed to projection
constexpr int M_PAD = 33024;        // 258*128 (tile-padded)
constexpr int DIM   = 1024;

DEV u16 f2bf(float x) {
  unsigned u = __float_as_uint(x);
  return (u16)((u + 0x7FFFu + ((u >> 16) & 1u)) >> 16);
}
DEV float bf2f(u16 s) { return __uint_as_float(((unsigned)s) << 16); }

DEV void gl2lds16(const void* g, void* l) {
  __builtin_amdgcn_global_load_lds(
      (const __attribute__((address_space(1))) unsigned int*)g,
      (__attribute__((address_space(3))) unsigned int*)l, 16, 0, 0);
}

#define MF(A, B, C) __builtin_amdgcn_mfma_f32_16x16x32_bf16(A, B, C, 0, 0, 0)
#define LFC(P, OFF) (*(const bf16x8*)((P) + (OFF)))

// ---------------- v3 core: 256x256, BK=32, 4 LDS buffers, 1 barrier/tile ----------
// Swizzle v3 (octet-bijective, HW-verified R15: conflicts -> 0): phys k-block =
// logical ^ ((row>>1)&3); per-octet 16B-slot (addr[6:4]) bijective over row&7.
// Stage: linear LDS dest + inverse-permuted global source (rule 21 matched pair).
// Counted vmcnt(4); no setprio / sched_barrier / lgkm asm.

#define STG(G, LT, R0) gl2lds16((G) + (R0) * 2048 + gOff, (LT) + (R0) * 64 + ldOff)

#define S_TILE(AT, BT, BUF)                                                           \
  { const char* ga_ = (AT); const char* gb_ = (BT); char* lb_ = (BUF);                \
    STG(ga_, lb_, 0); STG(ga_, lb_, 128);                                             \
    STG(gb_, lb_ + 16384, 0); STG(gb_, lb_ + 16384, 128); }

#define VMC4 asm volatile("s_waitcnt vmcnt(4)" ::: "memory");
#define VMC0 asm volatile("s_waitcnt vmcnt(0)" ::: "memory");

#define TILEV3(BUF, STAGES, WAIT)                                                     \
  {                                                                                   \
    STAGES                                                                            \
    const char* Ar = (BUF) + rdA;                                                     \
    const char* Br = (BUF) + 16384 + rdB;                                             \
    bf16x8 a0 = LFC(Ar, 0),    a1 = LFC(Ar, 1024), a2 = LFC(Ar, 2048), a3 = LFC(Ar, 3072); \
    bf16x8 a4 = LFC(Ar, 4096), a5 = LFC(Ar, 5120), a6 = LFC(Ar, 6144), a7 = LFC(Ar, 7168); \
    bf16x8 c0 = LFC(Br, 0), c1 = LFC(Br, 1024), c2 = LFC(Br, 2048), c3 = LFC(Br, 3072);    \
    acc[0][0] = MF(a0, c0, acc[0][0]); acc[0][1] = MF(a0, c1, acc[0][1]);             \
    acc[0][2] = MF(a0, c2, acc[0][2]); acc[0][3] = MF(a0, c3, acc[0][3]);             \
    acc[1][0] = MF(a1, c0, acc[1][0]); acc[1][1] = MF(a1, c1, acc[1][1]);             \
    acc[1][2] = MF(a1, c2, acc[1][2]); acc[1][3] = MF(a1, c3, acc[1][3]);             \
    acc[2][0] = MF(a2, c0, acc[2][0]); acc[2][1] = MF(a2, c1, acc[2][1]);             \
    acc[2][2] = MF(a2, c2, acc[2][2]); acc[2][3] = MF(a2, c3, acc[2][3]);             \
    acc[3][0] = MF(a3, c0, acc[3][0]); acc[3][1] = MF(a3, c1, acc[3][1]);             \
    acc[3][2] = MF(a3, c2, acc[3][2]); acc[3][3] = MF(a3, c3, acc[3][3]);             \
    acc[4][0] = MF(a4, c0, acc[4][0]); acc[4][1] = MF(a4, c1, acc[4][1]);             \
    acc[4][2] = MF(a4, c2, acc[4][2]); acc[4][3] = MF(a4, c3, acc[4][3]);             \
    acc[5][0] = MF(a5, c0, acc[5][0]); acc[5][1] = MF(a5, c1, acc[5][1]);             \
    acc[5][2] = MF(a5, c2, acc[5][2]); acc[5][3] = MF(a5, c3, acc[5][3]);             \
    acc[6][0] = MF(a6, c0, acc[6][0]); acc[6][1] = MF(a6, c1, acc[6][1]);             \
    acc[6][2] = MF(a6, c2, acc[6][2]); acc[6][3] = MF(a6, c3, acc[6][3]);             \
    acc[7][0] = MF(a7, c0, acc[7][0]); acc[7][1] = MF(a7, c1, acc[7][1]);             \
    acc[7][2] = MF(a7, c2, acc[7][2]); acc[7][3] = MF(a7, c3, acc[7][3]);             \
    WAIT                                                                              \
    asm volatile("s_barrier" ::: "memory");                                           \
  }

#define CORE_BASES                                                                    \
  const int ldOff = tid * 16;                                                         \
  const int gOff = (tid >> 2) * 2048 + (((tid & 3) ^ ((tid >> 3) & 3)) << 4);         \
  const int blk_ = (((lane >> 4) ^ ((lane >> 1) & 3)) << 4);                          \
  const int rdA = (wm + (lane & 15)) * 64 + blk_;                                     \
  const int rdB = (wn + (lane & 15)) * 64 + blk_;                                     \
  char* b0_ = lds; char* b1_ = lds + 32768; char* b2_ = lds + 65536; char* b3_ = lds + 98304;

#define GROUP4(T0)                                                                    \
    TILEV3(b0_, S_TILE(Ab((T0) + 2), Bb((T0) + 2), b2_), VMC4)                        \
    TILEV3(b1_, S_TILE(Ab((T0) + 3), Bb((T0) + 3), b3_), VMC4)                        \
    TILEV3(b2_, S_TILE(Ab((T0) + 4), Bb((T0) + 4), b0_), VMC4)                        \
    TILEV3(b3_, S_TILE(Ab((T0) + 5), Bb((T0) + 5), b1_), VMC4)

// ---------------- prep_all: all elementwise prep in ONE dispatch -------------------
// ranges: [0,8192) pack_w12 | [8192,11264) cast lin | [11264,15360) conv_w1 |
// [15360,19456) conv_w2 | [19456,23552) conv_w3 | [23552,24320) zero cat |
// [24320,57344) gather_cast

__global__ __launch_bounds__(256)
void prep_all(const float* __restrict__ w1, const float* __restrict__ w2,
              u16* __restrict__ W12,
              const float* __restrict__ lin_w, u16* __restrict__ linb,
              const float* __restrict__ cw1, const float* __restrict__ cw2,
              const float* __restrict__ cw3, u16* __restrict__ cwb,
              float* __restrict__ cat,
              const int* __restrict__ dq, const int* __restrict__ das,
              const float* __restrict__ emb, u16* __restrict__ X) {
  const int b = blockIdx.x, t = threadIdx.x;
  if (b < 8192) {                      // pack_w12: 16-row interleave of w1/w2
    int i = b * 256 + t;               // over 2048*1024
    int n2 = i >> 10, k = i & 1023;
    int j = n2 >> 4, m = n2 & 15;
    const float* src = (j & 1) ? w2 : w1;
    W12[i] = f2bf(src[(size_t)((j >> 1) * 16 + m) * 1024 + k]);
  } else if (b < 11264) {              // cast lin_w (float4 -> u16x4)
    int i = (b - 8192) * 256 + t;      // over 786432 float4s
    float4 v = ((const float4*)lin_w)[i];
    u16x4 o = { f2bf(v.x), f2bf(v.y), f2bf(v.z), f2bf(v.w) };
    ((u16x4*)linb)[i] = o;
  } else if (b < 23552) {              // conv weights: cw[o][i][k] -> W slabs
    int rb = b - 11264;
    int W = 1 + (rb >> 12);            // 4096 blocks per W in {1,2,3}
    int i = (rb & 4095) * 256 + t;     // over 1024*1024
    const float* src = (W == 1) ? cw1 : (W == 2) ? cw2 : cw3;
    u16* dst = cwb + ((W == 1) ? 0 : (W == 2) ? (size_t)1 * 1048576 : (size_t)3 * 1048576);
#pragma unroll 3
    for (int k = 0; k < 3; ++k)
      if (k < W)
        dst[(size_t)k * 1048576 + i] = f2bf(src[(size_t)i * W + k]);
  } else if (b < 24320) {              // zero cat [64][3072] f32
    cat[(b - 23552) * 256 + t] = 0.f;
  } else {                             // gather_cast
    const int row = b - 24320;         // [0, M_PAD)
    size_t dsto = (size_t)row * DIM + t * 4;
    if (row >= M_ALL) {
      u16x4 z = {0, 0, 0, 0};
      *(u16x4*)(X + dsto) = z;
      return;
    }
    const int tok = (row < T_ANS) ? das[row] : dq[row - T_ANS];
    float4 v = ((const float4*)(emb + (size_t)tok * DIM))[t];
    u16x4 o = { f2bf(v.x), f2bf(v.y), f2bf(v.z), f2bf(v.w) };
    *(u16x4*)(X + dsto) = o;
  }
}

__global__ void transpose_pq(const u16* __restrict__ pa, u16* __restrict__ pqT) {
  int i = blockIdx.x * 256 + threadIdx.x;  // 1024*64
  int e = i >> 6, q = i & 63;
  pqT[i] = pa[(size_t)(T_ANS + q) * DIM + e];
}

__global__ void zero_pad_sim(u16* __restrict__ sim) {
  int i = blockIdx.x * 256 + threadIdx.x;
  if (i < 2 * DIM) sim[(size_t)T_ANS * DIM + i] = 0;
}

__global__ void cast_cat(const float* __restrict__ cat, u16* __restrict__ catb) {
  int i = blockIdx.x * 256 + threadIdx.x;  // 128*3072
  if (i < 128 * 3072) {
    int row = i / 3072;
    catb[i] = (row < 64) ? f2bf(cat[i]) : (u16)0;
  }
}

// ---------------- projection, m97 structure + octet-bijective swizzle --------------
// 128x128 tile, 256 thr (4 waves, 64x64/wave), BK=32, single-buffer 16KB LDS.
// Swizzle v3 matched pair: stage source col-block ^= ((row>>1)&3); read 16B-block
// = (lane>>4) ^ ((lane>>1)&3) (lane-constant; wm/wn mult of 64, frag rows +16).

__global__ __launch_bounds__(256)
void proj_g(const u16* __restrict__ X, const u16* __restrict__ W12,
            const float* __restrict__ b1, const float* __restrict__ b2,
            u16* __restrict__ pa) {
  __shared__ alignas(16) u16 sA[128 * 32];
  __shared__ alignas(16) u16 sB[128 * 32];
  const int tid = threadIdx.x, lane = tid & 63;
  const int wid = tid >> 6;
  const int wm = (wid >> 1) * 64, wn = (wid & 1) * 64;
  // bijective XCD swizzle, tn fastest: 4128 = 8*516; 16 same-A blocks contiguous/XCD
  const int wg = ((int)blockIdx.x % 8) * 516 + (int)blockIdx.x / 8;
  const int tm = (wg >> 4) * 128, tn = (wg & 15) * 128;
  f32x4 acc[4][4] = {};
  for (int k0 = 0; k0 < 1024; k0 += 32) {
#pragma unroll
    for (int j = 0; j < 2; ++j) {
      const int f = tid * 16 + j * 4096;
      const int r = f >> 6;
      const int cb = (((f >> 4) & 3) ^ ((f >> 7) & 3)) << 4;  // inverse-swz source
      gl2lds16((const char*)X   + (size_t)(tm + r) * 2048 + k0 * 2 + cb, (char*)sA + f);
      gl2lds16((const char*)W12 + (size_t)(tn + r) * 2048 + k0 * 2 + cb, (char*)sB + f);
    }
    __syncthreads();
    const int lr = lane & 15;
    const int lk = ((lane >> 4) ^ ((lane >> 1) & 3)) * 8;      // swizzled 16B block
    bf16x8 af[4], bf[4];
#pragma unroll
    for (int i = 0; i < 4; ++i) {
      af[i] = *(const bf16x8*)(sA + (wm + i * 16 + lr) * 32 + lk);
      bf[i] = *(const bf16x8*)(sB + (wn + i * 16 + lr) * 32 + lk);
    }
#pragma unroll
    for (int mi = 0; mi < 4; ++mi)
#pragma unroll
      for (int ni = 0; ni < 4; ++ni)
        acc[mi][ni] = MF(af[mi], bf[ni], acc[mi][ni]);
    __syncthreads();
  }
  // epilogue: W12 interleave -> (sig, tanh) pairs at (ni, ni+1), ni even
  const int lr = lane & 15, lg = (lane >> 4) * 4;
#pragma unroll
  for (int np = 0; np < 2; ++np) {
    const int col = ((tn + wn) >> 1) + np * 16 + lr;   // output col 0..1023
    const float b1v = b1[col], b2v = b2[col];
#pragma unroll
    for (int mi = 0; mi < 4; ++mi)
#pragma unroll
      for (int r = 0; r < 4; ++r) {
        const int row = tm + wm + mi * 16 + lg + r;
        const float x1 = acc[mi][2 * np][r] + b1v;
        const float x2 = acc[mi][2 * np + 1][r] + b2v;
        const float sg = 1.f / (1.f + __expf(-x1));
        const float th = 2.f / (1.f + __expf(-2.f * x2)) - 1.f;
        pa[(size_t)row * DIM + col] = f2bf(sg * th);
      }
  }
}

// ---------------- conv_fused: all three convs, one continuous 192-tile pipeline ----
// Unified tile index t in [0,192): slab = t>>5 (cwb layout is tap-contiguous:
// [c1t0][c2t0][c2t1][c3t0][c3t1][c3t2]); A-tap(g) = g-(g>0)-2*(g>2) = {0,0,1,0,1,2}.
// Epilogues (register-only + atomics) after tiles 32/96/192.

__global__ __launch_bounds__(512, 1)
void conv_fused(const u16* __restrict__ sim, const u16* __restrict__ cwb,
                const float* __restrict__ cb1, const float* __restrict__ cb2,
                const float* __restrict__ cb3, float* __restrict__ cat) {
  extern __shared__ char lds[];
  const int tid = threadIdx.x, lane = tid & 63;
  const int wid = tid >> 6;
  const int wm = (wid >> 2) * 128, wn = (wid & 3) * 64;
  const int lr = lane & 15;
  // bijective XCD swizzle: 512 = 8*64; same-A blocks (all 4 tn) contiguous per XCD
  const int wg = ((int)blockIdx.x % 8) * 64 + (int)blockIdx.x / 8;
  const int tm = (wg >> 2) * 256, tn = (wg & 3) * 256;
  const char* Ag = (const char*)sim + (size_t)tm * 2048;
  const char* Bg = (const char*)cwb + (size_t)tn * 2048;
  auto Ab = [&](int t) {
    const int g = t >> 5;
    const int tap = g - (g > 0) - 2 * (g > 2);   // {0,0,1,0,1,2}
    return Ag + tap * 2048 + ((t & 31) << 6);
  };
  auto Bb = [&](int t) { return Bg + (size_t)(t >> 5) * 2097152 + ((t & 31) << 6); };

  f32x4 acc[8][4] = {};
  CORE_BASES

  const int lg = (lane >> 4) * 4;
  const int n = tm >> 9;  // 256 | 512 so one answer per tile
  auto epi = [&](int W, const float* cb, int outoff) {
#pragma unroll
    for (int ni = 0; ni < 4; ++ni) {
      const int col = tn + wn + ni * 16 + lr;
      const float cbv = cb[col];
      float vmax = 0.f;
#pragma unroll
      for (int mi = 0; mi < 8; ++mi)
#pragma unroll
        for (int r = 0; r < 4; ++r) {
          const int t = tm + wm + mi * 16 + lg + r;
          float v = fmaxf(acc[mi][ni][r] + cbv, 0.f);
          if ((t & 511) > 512 - W) v = 0.f;  // window straddles answer boundary
          vmax = fmaxf(vmax, v);
        }
      vmax = fmaxf(vmax, __shfl_xor(vmax, 16));
      vmax = fmaxf(vmax, __shfl_xor(vmax, 32));
      if (lane < 16)
        atomicMax((int*)&cat[(size_t)n * 3072 + outoff + col], __float_as_int(vmax));
    }
#pragma unroll
    for (int i = 0; i < 8; ++i)
#pragma unroll
      for (int j = 0; j < 4; ++j) acc[i][j] = (f32x4){0.f, 0.f, 0.f, 0.f};
  };

  S_TILE(Ab(0), Bb(0), b0_) S_TILE(Ab(1), Bb(1), b1_)
  VMC4
  asm volatile("s_barrier" ::: "memory");
  for (int g = 0; g < 8; ++g) { GROUP4(4 * g) }          // tiles 0..31 (conv1)
  epi(1, cb1, 0);
  for (int g = 8; g < 24; ++g) { GROUP4(4 * g) }         // tiles 32..95 (conv2)
  epi(2, cb2, 1024);
  for (int g = 24; g < 47; ++g) { GROUP4(4 * g) }        // tiles 96..187 (conv3)
  {
    TILEV3(b0_, S_TILE(Ab(190), Bb(190), b2_), VMC4)     // tiles 188..191 + drain
    TILEV3(b1_, S_TILE(Ab(191), Bb(191), b3_), VMC4)
    TILEV3(b2_, , VMC0)
    TILEV3(b3_, , )
  }
  epi(3, cb3, 2048);
}

// ---------------- attention S = pa @ pq^T  (split-K x4, deterministic partials) ----

__global__ __launch_bounds__(256, 2)
void attn_s(const u16* __restrict__ pa, float* __restrict__ Spart) {
  __shared__ alignas(16) u16 sA[128 * 32];
  __shared__ alignas(16) u16 sB[64 * 32];
  const int tid = threadIdx.x, lane = tid & 63;
  const int tm = blockIdx.x * 128;
  const int kbase = blockIdx.y * 256;     // K chunk of 256
  const int wid = tid >> 6;
  const int wm = (wid >> 1) * 64, wn = (wid & 1) * 32;
  const u16* pq = pa + (size_t)T_ANS * DIM;
  f32x4 acc[4][2] = {};
  for (int k0 = kbase; k0 < kbase + 256; k0 += 32) {
#pragma unroll
    for (int j = 0; j < 2; ++j) {
      const int f = tid * 16 + j * 4096;
      const int r = f >> 6, cb = f & 63;
      gl2lds16((const char*)pa + (size_t)(tm + r) * 2048 + k0 * 2 + cb, (char*)sA + f);
    }
    {
      const int f = tid * 16;  // 4 KB, single issue
      const int r = f >> 6, cb = f & 63;
      gl2lds16((const char*)pq + (size_t)r * 2048 + k0 * 2 + cb, (char*)sB + f);
    }
    __syncthreads();
    const int lr = lane & 15, lk = (lane >> 4) * 8;
    bf16x8 af[4], bfr[2];
#pragma unroll
    for (int i = 0; i < 4; ++i)
      af[i] = *(const bf16x8*)(sA + (wm + i * 16 + lr) * 32 + lk);
#pragma unroll
    for (int i = 0; i < 2; ++i)
      bfr[i] = *(const bf16x8*)(sB + (wn + i * 16 + lr) * 32 + lk);
#pragma unroll
    for (int mi = 0; mi < 4; ++mi)
#pragma unroll
      for (int ni = 0; ni < 2; ++ni)
        acc[mi][ni] = MF(af[mi], bfr[ni], acc[mi][ni]);
    __syncthreads();
  }
  const int lr = lane & 15, lg = (lane >> 4) * 4;
  float* Sp = Spart + (size_t)blockIdx.y * (T_ANS * 64);
#pragma unroll
  for (int mi = 0; mi < 4; ++mi)
#pragma unroll
    for (int ni = 0; ni < 2; ++ni)
#pragma unroll
      for (int r = 0; r < 4; ++r) {
        const int row = tm + wm + mi * 16 + lg + r;
        const int col = wn + ni * 16 + lr;
        Sp[(size_t)row * 64 + col] = acc[mi][ni][r];
      }
}

__global__ void softmax64(const float* __restrict__ Spart, u16* __restrict__ alpha) {
  const int row = blockIdx.x * 4 + (threadIdx.x >> 6);
  const int lane = threadIdx.x & 63;
  const size_t o = (size_t)row * 64 + lane;
  float v = Spart[o] + Spart[(size_t)1 * T_ANS * 64 + o]
          + Spart[(size_t)2 * T_ANS * 64 + o] + Spart[(size_t)3 * T_ANS * 64 + o];
  float m = v;
#pragma unroll
  for (int o2 = 32; o2 > 0; o2 >>= 1) m = fmaxf(m, __shfl_xor(m, o2));
  const float e = __expf(v - m);
  float s = e;
#pragma unroll
  for (int o2 = 32; o2 > 0; o2 >>= 1) s += __shfl_xor(s, o2);
  alpha[(size_t)row * 64 + lane] = f2bf(e / s);
}

// ---------------- Y = alpha @ pq ; sim = pa * Y ----------------

__global__ __launch_bounds__(256, 2)
void attn_y_sim(const u16* __restrict__ alpha, const u16* __restrict__ pqT,
                const u16* __restrict__ pa, u16* __restrict__ sim) {
  __shared__ alignas(16) u16 sA[128 * 32];
  __shared__ alignas(16) u16 sB[128 * 32];
  const int tid = threadIdx.x, lane = tid & 63;
  const int tm = blockIdx.x * 128, tn = blockIdx.y * 128;
  const int wid = tid >> 6;
  const int wm = (wid >> 1) * 64, wn = (wid & 1) * 64;
  f32x4 acc[4][4] = {};
  for (int k0 = 0; k0 < 64; k0 += 32) {
#pragma unroll
    for (int j = 0; j < 2; ++j) {
      const int f = tid * 16 + j * 4096;
      const int r = f >> 6, cb = f & 63;
      gl2lds16((const char*)alpha + (size_t)(tm + r) * 128 + k0 * 2 + cb, (char*)sA + f);
      gl2lds16((const char*)pqT   + (size_t)(tn + r) * 128 + k0 * 2 + cb, (char*)sB + f);
    }
    __syncthreads();
    const int lr = lane & 15, lk = (lane >> 4) * 8;
    bf16x8 af[4], bfr[4];
#pragma unroll
    for (int i = 0; i < 4; ++i) {
      af[i]  = *(const bf16x8*)(sA + (wm + i * 16 + lr) * 32 + lk);
      bfr[i] = *(const bf16x8*)(sB + (wn + i * 16 + lr) * 32 + lk);
    }
#pragma unroll
    for (int mi = 0; mi < 4; ++mi)
#pragma unroll
      for (int ni = 0; ni < 4; ++ni)
        acc[mi][ni] = MF(af[mi], bfr[ni], acc[mi][ni]);
    __syncthreads();
  }
  const int lr = lane & 15, lg = (lane >> 4) * 4;
#pragma unroll
  for (int ni = 0; ni < 4; ++ni) {
    const int col = tn + wn + ni * 16 + lr;
#pragma unroll
    for (int mi = 0; mi < 4; ++mi)
#pragma unroll
      for (int r = 0; r < 4; ++r) {
        const int row = tm + wm + mi * 16 + lg + r;
        const size_t o = (size_t)row * DIM + col;
        sim[o] = f2bf(bf2f(pa[o]) * acc[mi][ni][r]);
      }
  }
}

// ---------------- final: h = tanh(cat @ lin^T + b) ----------------

__global__ __launch_bounds__(256, 2)
void final_h(const u16* __restrict__ catb, const u16* __restrict__ linb,
             const float* __restrict__ lin_b, float* __restrict__ h) {
  __shared__ alignas(16) u16 sA[128 * 32];
  __shared__ alignas(16) u16 sB[128 * 32];
  const int tid = threadIdx.x, lane = tid & 63;
  const int tn = blockIdx.y * 128;
  const int wid = tid >> 6;
  const int wm = (wid >> 1) * 64, wn = (wid & 1) * 64;
  f32x4 acc[4][4] = {};
  for (int k0 = 0; k0 < 3072; k0 += 32) {
#pragma unroll
    for (int j = 0; j < 2; ++j) {
      const int f = tid * 16 + j * 4096;
      const int r = f >> 6, cb = f & 63;
      gl2lds16((const char*)catb + (size_t)r * 6144 + k0 * 2 + cb, (char*)sA + f);
      gl2lds16((const char*)linb + (size_t)(tn + r) * 6144 + k0 * 2 + cb, (char*)sB + f);
    }
    __syncthreads();
    const int lr = lane & 15, lk = (lane >> 4) * 8;
    bf16x8 af[4], bfr[4];
#pragma unroll
    for (int i = 0; i < 4; ++i) {
      af[i]  = *(const bf16x8*)(sA + (wm + i * 16 + lr) * 32 + lk);
      bfr[i] = *(const bf16x8*)(sB + (wn + i * 16 + lr) * 32 + lk);
    }
#pragma unroll
    for (int mi = 0; mi < 4; ++mi)
#pragma unroll
      for (int ni = 0; ni < 4; ++ni)
        acc[mi][ni] = MF(af[mi], bfr[ni], acc[mi][ni]);
    __syncthreads();
  }
  const int lr = lane & 15, lg = (lane >> 4) * 4;
#pragma unroll
  for (int ni = 0; ni < 4; ++ni) {
    const int col = tn + wn + ni * 16 + lr;
    const float bv = lin_b[col];
#pragma unroll
    for (int mi = 0; mi < 4; ++mi)
#pragma unroll
      for (int r = 0; r < 4; ++r) {
        const int row = wm + mi * 16 + lg + r;
        if (row < 64) {
          const float x = acc[mi][ni][r] + bv;
          h[(size_t)row * DIM + col] = 2.f / (1.f + __expf(-2.f * x)) - 1.f;
        }
      }
  }
}

__global__ void final_logits(const float* __restrict__ h, const float* __restrict__ soft_w,
                             const float* __restrict__ soft_b, float* __restrict__ out) {
  __shared__ float part[256];
  const int t = threadIdx.x;
  const int n = t >> 2, q = t & 3;
  float s = 0.f;
  for (int j = q * 256; j < q * 256 + 256; ++j) s += h[(size_t)n * DIM + j] * soft_w[j];
  part[t] = s;
  __syncthreads();
  if (t < 64) {
    float logit = part[t * 4] + part[t * 4 + 1] + part[t * 4 + 2] + part[t * 4 + 3] + soft_b[0];
    float m = logit;
#pragma unroll
    for (int o = 32; o > 0; o >>= 1) m = fmaxf(m, __shfl_xor(m, o));
    float e = __expf(logit - m);
    float ssum = e;
#pragma unroll
    for (int o = 32; o > 0; o >>= 1) ssum += __shfl_xor(ssum, o);
    out[t] = (logit - m) - logf(ssum);
  }
}

// ---------------- launcher ----------------

extern "C" void kernel_launch(void* const* d_in, const int* in_sizes, int n_in,
                              void* d_out, int out_size, void* d_ws, size_t ws_size,
                              hipStream_t stream) {
  const int*   data_q  = (const int*)d_in[0];
  const int*   data_as = (const int*)d_in[1];
  const float* emb     = (const float*)d_in[2];
  const float* w1      = (const float*)d_in[3];
  const float* b1      = (const float*)d_in[4];
  const float* w2      = (const float*)d_in[5];
  const float* b2      = (const float*)d_in[6];
  const float* cw1     = (const float*)d_in[7];
  const float* cb1     = (const float*)d_in[8];
  const float* cw2     = (const float*)d_in[9];
  const float* cb2     = (const float*)d_in[10];
  const float* cw3     = (const float*)d_in[11];
  const float* cb3     = (const float*)d_in[12];
  const float* lin_w   = (const float*)d_in[13];
  const float* lin_b   = (const float*)d_in[14];
  const float* soft_w  = (const float*)d_in[15];
  const float* soft_b  = (const float*)d_in[16];
  float* out = (float*)d_out;

  // allow 128 KiB dynamic LDS on the fused conv kernel (host attr set, capture-safe)
  hipFuncSetAttribute((const void*)conv_fused, hipFuncAttributeMaxDynamicSharedMemorySize, 131072);

  // workspace layout (~167 MB total)
  u16* X     = (u16*)d_ws;                         // [M_PAD][1024] bf16; reused: Spart, then sim
  u16* pa    = X    + (size_t)M_PAD * DIM;         // [M_PAD][1024] bf16 (rows T..T+63 = pq)
  u16* W12   = pa   + (size_t)M_PAD * DIM;         // [2048][1024] interleaved w1/w2
  u16* cwb   = W12  + (size_t)2 * 1024 * 1024;     // 6 x [1024][1024]
  u16* linb  = cwb  + (size_t)6 * 1024 * 1024;     // [1024][3072]
  u16* pqT   = linb + (size_t)3 * 1024 * 1024;     // [1024][64]
  u16* alpha = pqT  + 64 * 1024;                   // [T][64] bf16
  float* cat = (float*)(alpha + (size_t)T_ANS * 64);  // [64][3072] f32 pools
  u16* catb  = (u16*)(cat + 64 * 3072);            // [128][3072] bf16 (rows 64+ zero)
  float* h   = (float*)(catb + 128 * 3072);        // [64][1024] f32
  u16* simb  = X;                                  // alias: [T+2][1024] bf16
  float* Spart = (float*)X;                        // alias: [4][T][64] f32 (33.6 MB < 67 MB)

  prep_all<<<57344, 256, 0, stream>>>(w1, w2, W12, lin_w, linb, cw1, cw2, cw3, cwb,
                                      cat, data_q, data_as, emb, X);

  proj_g<<<4128, 256, 0, stream>>>(X, W12, b1, b2, pa);
  transpose_pq<<<256, 256, 0, stream>>>(pa, pqT);

  attn_s<<<dim3(T_ANS / 128, 4), 256, 0, stream>>>(pa, Spart);
  softmax64<<<T_ANS / 4, 256, 0, stream>>>(Spart, alpha);
  attn_y_sim<<<dim3(T_ANS / 128, 8), 256, 0, stream>>>(alpha, pqT, pa, simb);
  zero_pad_sim<<<8, 256, 0, stream>>>(simb);

  conv_fused<<<512, 512, 131072, stream>>>(simb, cwb, cb1, cb2, cb3, cat);

  cast_cat<<<1536, 256, 0, stream>>>(cat, catb);
  final_h<<<dim3(1, 8), 256, 0, stream>>>(catb, linb, lin_b, h);
  final_logits<<<1, 256, 0, stream>>>(h, soft_w, soft_b, out);
}